// Round 1
// baseline (1701.170 us; speedup 1.0000x reference)
//
#include <hip/hip_runtime.h>

#define NN 100000
#define EE 1200000
#define DD 64
#define CC 40
#define KK 16

// ---------- degree histogram: deg_cnt[dst[e]] += 1 ----------
__global__ __launch_bounds__(256) void deg_kernel(const int* __restrict__ dst,
                                                  int* __restrict__ cnt) {
    int e = blockIdx.x * 256 + threadIdx.x;
    if (e < EE) atomicAdd(&cnt[dst[e]], 1);
}

// ---------- dinv[i] = rsqrt(indeg+1) (self-loop included) ----------
__global__ __launch_bounds__(256) void dinv_kernel(const int* __restrict__ cnt,
                                                   float* __restrict__ dinv) {
    int i = blockIdx.x * 256 + threadIdx.x;
    if (i < NN) dinv[i] = rsqrtf((float)(cnt[i] + 1));
}

// ---------- single-block exclusive scan of cnt -> row_ptr[N+1] ----------
__global__ __launch_bounds__(1024) void scan_kernel(const int* __restrict__ cnt,
                                                    int* __restrict__ row_ptr) {
    __shared__ int sm[1024];
    int t = threadIdx.x;
    const int per = (NN + 1023) / 1024;  // 98
    int start = t * per;
    int end = start + per; if (end > NN) end = NN; if (start > NN) start = NN;
    int s = 0;
    for (int j = start; j < end; ++j) s += cnt[j];
    sm[t] = s;
    __syncthreads();
    // Hillis-Steele inclusive scan over 1024 partials
    for (int off = 1; off < 1024; off <<= 1) {
        int v = (t >= off) ? sm[t - off] : 0;
        __syncthreads();
        if (t >= off) sm[t] += v;
        __syncthreads();
    }
    int run = sm[t] - s;  // exclusive prefix of this thread's chunk
    for (int j = start; j < end; ++j) { row_ptr[j] = run; run += cnt[j]; }
    if (t == 1023) row_ptr[NN] = sm[1023];  // == EE
}

// ---------- scatter edges into CSR (counting sort by dst) ----------
__global__ __launch_bounds__(256) void scatter_kernel(
    const int* __restrict__ src, const int* __restrict__ dst,
    const int* __restrict__ row_ptr, int* __restrict__ cursor,
    int* __restrict__ col_idx, float* __restrict__ ew,
    const float* __restrict__ dinv) {
    int e = blockIdx.x * 256 + threadIdx.x;
    if (e >= EE) return;
    int d = dst[e], s = src[e];
    int pos = row_ptr[d] + atomicAdd(&cursor[d], 1);
    col_idx[pos] = s;
    ew[pos] = dinv[d] * dinv[s];
}

// ---------- fused SpMM (pull) + SSGC h-update ----------
// one wave per node; lane = feature dim. h updated in place.
__global__ __launch_bounds__(256) void spmm_step(
    const float* __restrict__ x, const float* __restrict__ feat,
    float* __restrict__ h, float* __restrict__ x_out,
    const int* __restrict__ row_ptr, const int* __restrict__ col_idx,
    const float* __restrict__ ew, const float* __restrict__ dinv) {
    int w = (blockIdx.x * 256 + threadIdx.x) >> 6;
    int lane = threadIdx.x & 63;
    if (w >= NN) return;
    int beg = row_ptr[w], end = row_ptr[w + 1];
    float di = dinv[w];
    long base = (long)w * DD + lane;
    float acc = di * di * x[base];  // self-loop
    int e = beg;
    for (; e + 1 < end; e += 2) {   // unroll x2: two gathers in flight
        int c0 = col_idx[e], c1 = col_idx[e + 1];
        float w0 = ew[e], w1 = ew[e + 1];
        float v0 = x[c0 * DD + lane];
        float v1 = x[c1 * DD + lane];
        acc = fmaf(w0, v0, acc);
        acc = fmaf(w1, v1, acc);
    }
    if (e < end) {
        int c0 = col_idx[e];
        acc = fmaf(ew[e], x[c0 * DD + lane], acc);
    }
    x_out[base] = acc;
    // h = (h + (1-alpha)*x_new + alpha*feat) / K
    h[base] = (h[base] + 0.95f * acc + 0.05f * feat[base]) * (1.0f / KK);
}

// ---------- FC epilogue: out[n,c] = h[n,:] . W[c,:] + b[c] ----------
__global__ __launch_bounds__(256) void fc_kernel(const float* __restrict__ h,
                                                 const float* __restrict__ W,
                                                 const float* __restrict__ b,
                                                 float* __restrict__ out) {
    __shared__ float Ws[CC * 68];  // stride 68 breaks the c*64 bank pattern
    __shared__ float bs[CC];
    for (int j = threadIdx.x; j < CC * DD; j += 256) {
        int c = j >> 6, d = j & 63;
        Ws[c * 68 + d] = W[j];
    }
    if (threadIdx.x < CC) bs[threadIdx.x] = b[threadIdx.x];
    __syncthreads();
    int idx = blockIdx.x * 256 + threadIdx.x;
    if (idx >= NN * CC) return;
    int i = idx / CC, c = idx - i * CC;
    const float4* h4 = (const float4*)(h + (long)i * DD);
    const float* wr = Ws + c * 68;
    float acc = bs[c];
#pragma unroll
    for (int d2 = 0; d2 < 16; ++d2) {
        float4 a = h4[d2];
        acc = fmaf(a.x, wr[d2 * 4 + 0], acc);
        acc = fmaf(a.y, wr[d2 * 4 + 1], acc);
        acc = fmaf(a.z, wr[d2 * 4 + 2], acc);
        acc = fmaf(a.w, wr[d2 * 4 + 3], acc);
    }
    out[idx] = acc;
}

extern "C" void kernel_launch(void* const* d_in, const int* in_sizes, int n_in,
                              void* d_out, int out_size, void* d_ws, size_t ws_size,
                              hipStream_t stream) {
    const float* feat = (const float*)d_in[0];
    const float* W    = (const float*)d_in[1];
    const float* b    = (const float*)d_in[2];
    const int*   src  = (const int*)d_in[3];
    const int*   dst  = (const int*)d_in[4];
    float* out = (float*)d_out;

    // carve workspace (~88 MB)
    char* p = (char*)d_ws;
    auto alloc = [&](size_t bytes) {
        char* r = p;
        p += (bytes + 255) & ~(size_t)255;
        return r;
    };
    int*   cnt     = (int*)alloc((size_t)NN * sizeof(int));
    int*   cursor  = (int*)alloc((size_t)NN * sizeof(int));
    float* dinv    = (float*)alloc((size_t)NN * sizeof(float));
    int*   row_ptr = (int*)alloc((size_t)(NN + 1) * sizeof(int));
    int*   col_idx = (int*)alloc((size_t)EE * sizeof(int));
    float* ew      = (float*)alloc((size_t)EE * sizeof(float));
    float* x0      = (float*)alloc((size_t)NN * DD * sizeof(float));
    float* x1      = (float*)alloc((size_t)NN * DD * sizeof(float));
    float* h       = (float*)alloc((size_t)NN * DD * sizeof(float));

    hipMemsetAsync(cnt, 0, (size_t)NN * sizeof(int), stream);
    hipMemsetAsync(cursor, 0, (size_t)NN * sizeof(int), stream);
    hipMemsetAsync(h, 0, (size_t)NN * DD * sizeof(float), stream);

    deg_kernel<<<(EE + 255) / 256, 256, 0, stream>>>(dst, cnt);
    dinv_kernel<<<(NN + 255) / 256, 256, 0, stream>>>(cnt, dinv);
    scan_kernel<<<1, 1024, 0, stream>>>(cnt, row_ptr);
    scatter_kernel<<<(EE + 255) / 256, 256, 0, stream>>>(src, dst, row_ptr, cursor,
                                                         col_idx, ew, dinv);

    const float* xs = feat;  // step 0 reads feat directly, no copy
    float* xd = x0;
    for (int k = 0; k < KK; ++k) {
        spmm_step<<<(NN * 64 + 255) / 256, 256, 0, stream>>>(xs, feat, h, xd,
                                                             row_ptr, col_idx, ew, dinv);
        xs = xd;
        xd = (xd == x0) ? x1 : x0;
    }
    fc_kernel<<<(NN * CC + 255) / 256, 256, 0, stream>>>(h, W, b, out);
}

// Round 2
// 849.493 us; speedup vs baseline: 2.0026x; 2.0026x over previous
//
#include <hip/hip_runtime.h>
#include <hip/hip_fp16.h>

#define NN 100000
#define EE 1200000
#define DD 64
#define CC 40
#define KK 16
#define SCAN_BLOCKS ((NN + 255) / 256)  // 391

struct __align__(8) ERec { int c; float w; };

// ---------- degree histogram ----------
__global__ __launch_bounds__(256) void deg_kernel(const int* __restrict__ dst,
                                                  int* __restrict__ cnt) {
    int e = blockIdx.x * 256 + threadIdx.x;
    if (e < EE) atomicAdd(&cnt[dst[e]], 1);
}

// ---------- dinv[i] = rsqrt(indeg+1) ----------
__global__ __launch_bounds__(256) void dinv_kernel(const int* __restrict__ cnt,
                                                   float* __restrict__ dinv) {
    int i = blockIdx.x * 256 + threadIdx.x;
    if (i < NN) dinv[i] = rsqrtf((float)(cnt[i] + 1));
}

// ---------- 3-phase coalesced exclusive scan ----------
__global__ __launch_bounds__(256) void scan1_kernel(const int* __restrict__ cnt,
                                                    int* __restrict__ row_ptr,
                                                    int* __restrict__ bsum) {
    __shared__ int sm[256];
    int t = threadIdx.x;
    int i = blockIdx.x * 256 + t;
    int v = (i < NN) ? cnt[i] : 0;
    sm[t] = v;
    __syncthreads();
    for (int off = 1; off < 256; off <<= 1) {
        int u = (t >= off) ? sm[t - off] : 0;
        __syncthreads();
        sm[t] += u;
        __syncthreads();
    }
    if (i < NN) row_ptr[i] = sm[t] - v;  // block-local exclusive
    if (t == 255) bsum[blockIdx.x] = sm[255];
}

__global__ __launch_bounds__(512) void scan2_kernel(const int* __restrict__ bsum,
                                                    int* __restrict__ boff) {
    __shared__ int sm[512];
    int t = threadIdx.x;
    int v = (t < SCAN_BLOCKS) ? bsum[t] : 0;
    sm[t] = v;
    __syncthreads();
    for (int off = 1; off < 512; off <<= 1) {
        int u = (t >= off) ? sm[t - off] : 0;
        __syncthreads();
        sm[t] += u;
        __syncthreads();
    }
    if (t < SCAN_BLOCKS) boff[t] = sm[t] - v;
}

__global__ __launch_bounds__(256) void scan3_kernel(int* __restrict__ row_ptr,
                                                    const int* __restrict__ boff) {
    int i = blockIdx.x * 256 + threadIdx.x;
    if (i < NN) row_ptr[i] += boff[blockIdx.x];
    if (i == 0) row_ptr[NN] = EE;
}

// ---------- scatter edges into CSR, packed (col, w) records ----------
__global__ __launch_bounds__(256) void scatter_kernel(
    const int* __restrict__ src, const int* __restrict__ dst,
    const int* __restrict__ row_ptr, int* __restrict__ cursor,
    int2* __restrict__ er, const float* __restrict__ dinv) {
    int e = blockIdx.x * 256 + threadIdx.x;
    if (e >= EE) return;
    int d = dst[e], s = src[e];
    int pos = row_ptr[d] + atomicAdd(&cursor[d], 1);
    float w = dinv[d] * dinv[s];
    er[pos] = make_int2(s, __float_as_int(w));
}

// ---------- feat (fp32) -> x0 (fp16) ----------
__global__ __launch_bounds__(256) void cvt_kernel(const float2* __restrict__ feat2,
                                                  __half2* __restrict__ xh) {
    int i = blockIdx.x * 256 + threadIdx.x;
    if (i < NN * 32) {
        float2 f = feat2[i];
        xh[i] = __floats2half2_rn(f.x, f.y);
    }
}

// ---------- fused SpMM (pull, fp16 x) + SSGC h-update ----------
// 32 lanes per node (half2 = 2 dims/lane), 2 nodes per wave.
// mode: 0 = no h update (early steps), 1 = h update, 2 = h update + feat term
__global__ __launch_bounds__(256) void spmm_step(
    const __half2* __restrict__ x, float2* __restrict__ h,
    __half2* __restrict__ x_out, const float2* __restrict__ feat2,
    const int* __restrict__ row_ptr, const ERec* __restrict__ er,
    const float* __restrict__ dinv, int mode) {
    int wid = (blockIdx.x * 256 + threadIdx.x) >> 6;
    int lane = threadIdx.x & 63;
    int node = wid * 2 + (lane >> 5);
    int li = lane & 31;
    int beg = row_ptr[node], end = row_ptr[node + 1];
    float di = dinv[node];
    int base = node * 32 + li;
    float2 self = __half22float2(x[base]);
    float w0 = di * di;
    float ax = w0 * self.x, ay = w0 * self.y;
    int e = beg;
    int e4 = beg + ((end - beg) & ~3);
    for (; e < e4; e += 4) {  // unroll x4: 4 gathers in flight
        ERec r0 = er[e], r1 = er[e + 1], r2 = er[e + 2], r3 = er[e + 3];
        float2 v0 = __half22float2(x[r0.c * 32 + li]);
        float2 v1 = __half22float2(x[r1.c * 32 + li]);
        float2 v2 = __half22float2(x[r2.c * 32 + li]);
        float2 v3 = __half22float2(x[r3.c * 32 + li]);
        ax = fmaf(r0.w, v0.x, ax); ay = fmaf(r0.w, v0.y, ay);
        ax = fmaf(r1.w, v1.x, ax); ay = fmaf(r1.w, v1.y, ay);
        ax = fmaf(r2.w, v2.x, ax); ay = fmaf(r2.w, v2.y, ay);
        ax = fmaf(r3.w, v3.x, ax); ay = fmaf(r3.w, v3.y, ay);
    }
    for (; e < end; ++e) {
        ERec r = er[e];
        float2 v = __half22float2(x[r.c * 32 + li]);
        ax = fmaf(r.w, v.x, ax); ay = fmaf(r.w, v.y, ay);
    }
    x_out[base] = __floats2half2_rn(ax, ay);
    if (mode) {
        float2 hv = h[base];
        hv.x = (hv.x + 0.95f * ax) * (1.0f / 16.0f);
        hv.y = (hv.y + 0.95f * ay) * (1.0f / 16.0f);
        if (mode == 2) {
            // analytic feat term: 0.05 * sum_{j=1..16} 16^-j = 0.05/15 (16^-16 ~ 5e-20)
            const float FC = 0.05f / 15.0f;
            float2 f = feat2[base];
            hv.x = fmaf(FC, f.x, hv.x);
            hv.y = fmaf(FC, f.y, hv.y);
        }
        h[base] = hv;
    }
}

// ---------- FC epilogue ----------
__global__ __launch_bounds__(256) void fc_kernel(const float* __restrict__ h,
                                                 const float* __restrict__ W,
                                                 const float* __restrict__ b,
                                                 float* __restrict__ out) {
    __shared__ float Ws[CC * 68];
    __shared__ float bs[CC];
    for (int j = threadIdx.x; j < CC * DD; j += 256) {
        int c = j >> 6, d = j & 63;
        Ws[c * 68 + d] = W[j];
    }
    if (threadIdx.x < CC) bs[threadIdx.x] = b[threadIdx.x];
    __syncthreads();
    int idx = blockIdx.x * 256 + threadIdx.x;
    if (idx >= NN * CC) return;
    int i = idx / CC, c = idx - i * CC;
    const float4* h4 = (const float4*)(h + (long)i * DD);
    const float* wr = Ws + c * 68;
    float acc = bs[c];
#pragma unroll
    for (int d2 = 0; d2 < 16; ++d2) {
        float4 a = h4[d2];
        acc = fmaf(a.x, wr[d2 * 4 + 0], acc);
        acc = fmaf(a.y, wr[d2 * 4 + 1], acc);
        acc = fmaf(a.z, wr[d2 * 4 + 2], acc);
        acc = fmaf(a.w, wr[d2 * 4 + 3], acc);
    }
    out[idx] = acc;
}

extern "C" void kernel_launch(void* const* d_in, const int* in_sizes, int n_in,
                              void* d_out, int out_size, void* d_ws, size_t ws_size,
                              hipStream_t stream) {
    const float* feat = (const float*)d_in[0];
    const float* W    = (const float*)d_in[1];
    const float* b    = (const float*)d_in[2];
    const int*   src  = (const int*)d_in[3];
    const int*   dst  = (const int*)d_in[4];
    float* out = (float*)d_out;

    char* p = (char*)d_ws;
    auto alloc = [&](size_t bytes) {
        char* r = p;
        p += (bytes + 255) & ~(size_t)255;
        return r;
    };
    int*      cnt     = (int*)alloc((size_t)NN * sizeof(int));
    int*      cursor  = (int*)alloc((size_t)NN * sizeof(int));
    float*    dinv    = (float*)alloc((size_t)NN * sizeof(float));
    int*      row_ptr = (int*)alloc((size_t)(NN + 1) * sizeof(int));
    int*      bsum    = (int*)alloc((size_t)SCAN_BLOCKS * sizeof(int));
    int*      boff    = (int*)alloc((size_t)SCAN_BLOCKS * sizeof(int));
    int2*     er      = (int2*)alloc((size_t)EE * sizeof(int2));
    __half2*  xh0     = (__half2*)alloc((size_t)NN * 32 * sizeof(__half2));
    __half2*  xh1     = (__half2*)alloc((size_t)NN * 32 * sizeof(__half2));
    float*    h       = (float*)alloc((size_t)NN * DD * sizeof(float));

    hipMemsetAsync(cnt, 0, (size_t)NN * sizeof(int), stream);
    hipMemsetAsync(cursor, 0, (size_t)NN * sizeof(int), stream);
    hipMemsetAsync(h, 0, (size_t)NN * DD * sizeof(float), stream);

    deg_kernel<<<(EE + 255) / 256, 256, 0, stream>>>(dst, cnt);
    dinv_kernel<<<(NN + 255) / 256, 256, 0, stream>>>(cnt, dinv);
    scan1_kernel<<<SCAN_BLOCKS, 256, 0, stream>>>(cnt, row_ptr, bsum);
    scan2_kernel<<<1, 512, 0, stream>>>(bsum, boff);
    scan3_kernel<<<SCAN_BLOCKS, 256, 0, stream>>>(row_ptr, boff);
    scatter_kernel<<<(EE + 255) / 256, 256, 0, stream>>>(src, dst, row_ptr, cursor,
                                                         er, dinv);
    cvt_kernel<<<(NN * 32 + 255) / 256, 256, 0, stream>>>((const float2*)feat, xh0);

    const __half2* xs = xh0;
    __half2* xd = xh1;
    for (int j = 0; j < KK; ++j) {
        int mode = (j >= 10) ? ((j == KK - 1) ? 2 : 1) : 0;
        // 50000 waves (2 nodes each) -> 12500 blocks of 256
        spmm_step<<<12500, 256, 0, stream>>>(xs, (float2*)h, xd, (const float2*)feat,
                                             row_ptr, (const ERec*)er, dinv, mode);
        const __half2* t = xd;
        xd = (xd == xh0) ? xh1 : xh0;
        xs = t;
    }
    fc_kernel<<<(NN * CC + 255) / 256, 256, 0, stream>>>(h, W, b, out);
}

// Round 3
// 765.472 us; speedup vs baseline: 2.2224x; 1.1098x over previous
//
#include <hip/hip_runtime.h>
#include <hip/hip_fp16.h>

#define NN 100000
#define EE 1200000
#define DD 64
#define CC 40
#define KK 16
#define SCAN_BLOCKS ((NN + 255) / 256)  // 391

struct __align__(8) ERec { int c; float w; };

// ---------- degree histogram ----------
__global__ __launch_bounds__(256) void deg_kernel(const int* __restrict__ dst,
                                                  int* __restrict__ cnt) {
    int e = blockIdx.x * 256 + threadIdx.x;
    if (e < EE) atomicAdd(&cnt[dst[e]], 1);
}

// ---------- dinv[i] = rsqrt(indeg+1) ----------
__global__ __launch_bounds__(256) void dinv_kernel(const int* __restrict__ cnt,
                                                   float* __restrict__ dinv) {
    int i = blockIdx.x * 256 + threadIdx.x;
    if (i < NN) dinv[i] = rsqrtf((float)(cnt[i] + 1));
}

// ---------- 3-phase coalesced exclusive scan ----------
__global__ __launch_bounds__(256) void scan1_kernel(const int* __restrict__ cnt,
                                                    int* __restrict__ row_ptr,
                                                    int* __restrict__ bsum) {
    __shared__ int sm[256];
    int t = threadIdx.x;
    int i = blockIdx.x * 256 + t;
    int v = (i < NN) ? cnt[i] : 0;
    sm[t] = v;
    __syncthreads();
    for (int off = 1; off < 256; off <<= 1) {
        int u = (t >= off) ? sm[t - off] : 0;
        __syncthreads();
        sm[t] += u;
        __syncthreads();
    }
    if (i < NN) row_ptr[i] = sm[t] - v;  // block-local exclusive
    if (t == 255) bsum[blockIdx.x] = sm[255];
}

__global__ __launch_bounds__(512) void scan2_kernel(const int* __restrict__ bsum,
                                                    int* __restrict__ boff) {
    __shared__ int sm[512];
    int t = threadIdx.x;
    int v = (t < SCAN_BLOCKS) ? bsum[t] : 0;
    sm[t] = v;
    __syncthreads();
    for (int off = 1; off < 512; off <<= 1) {
        int u = (t >= off) ? sm[t - off] : 0;
        __syncthreads();
        sm[t] += u;
        __syncthreads();
    }
    if (t < SCAN_BLOCKS) boff[t] = sm[t] - v;
}

__global__ __launch_bounds__(256) void scan3_kernel(int* __restrict__ row_ptr,
                                                    const int* __restrict__ boff) {
    int i = blockIdx.x * 256 + threadIdx.x;
    if (i < NN) row_ptr[i] += boff[blockIdx.x];
    if (i == 0) row_ptr[NN] = EE;
}

// ---------- pass A: scatter only a 4B permutation index ----------
// 4.8 MB window ~ L2-resident -> far less write amplification than 8B recs
__global__ __launch_bounds__(256) void perm_kernel(const int* __restrict__ dst,
                                                   const int* __restrict__ row_ptr,
                                                   int* __restrict__ cursor,
                                                   int* __restrict__ perm) {
    int e = blockIdx.x * 256 + threadIdx.x;
    if (e >= EE) return;
    int d = dst[e];
    int pos = row_ptr[d] + atomicAdd(&cursor[d], 1);
    perm[pos] = e;
}

// ---------- pass B: sequential er build (writes coalesced, reads gather) ----------
__global__ __launch_bounds__(256) void build_kernel(const int* __restrict__ perm,
                                                    const int* __restrict__ src,
                                                    const int* __restrict__ dst,
                                                    const float* __restrict__ dinv,
                                                    int2* __restrict__ er) {
    int p = blockIdx.x * 256 + threadIdx.x;
    if (p >= EE) return;
    int e = perm[p];
    int s = src[e], d = dst[e];
    float w = dinv[d] * dinv[s];
    er[p] = make_int2(s, __float_as_int(w));
}

// ---------- feat (fp32) -> x0 (fp16) ----------
__global__ __launch_bounds__(256) void cvt_kernel(const float2* __restrict__ feat2,
                                                  __half2* __restrict__ xh) {
    int i = blockIdx.x * 256 + threadIdx.x;
    if (i < NN * 32) {
        float2 f = feat2[i];
        xh[i] = __floats2half2_rn(f.x, f.y);
    }
}

// ---------- fused SpMM (pull, fp16 x) + SSGC h-update ----------
// 8 lanes/node (float4 = 8 halves each), 8 nodes/wave, unroll x4:
// up to 32 outstanding 128B gather transactions per wave.
// mode: 0 = no h update, 1 = h update, 2 = h update + analytic feat term
__global__ __launch_bounds__(256) void spmm_step(
    const float4* __restrict__ x, float4* __restrict__ x_out,
    float4* __restrict__ h4, const float4* __restrict__ feat4,
    const int* __restrict__ row_ptr, const ERec* __restrict__ er,
    const float* __restrict__ dinv, int mode) {
    int g = (blockIdx.x * 256 + threadIdx.x) >> 3;  // node; grid is exact (NN*8 threads)
    int li = threadIdx.x & 7;                       // owns dims [8li, 8li+8)
    int beg = row_ptr[g], end = row_ptr[g + 1];
    float di = dinv[g];
    float w0 = di * di;
    int base = g * 8 + li;
    float4 sv = x[base];
    float a0, a1, a2, a3, a4, a5, a6, a7;
    {
        const __half2* hp = (const __half2*)&sv;
        float2 f0 = __half22float2(hp[0]), f1 = __half22float2(hp[1]);
        float2 f2 = __half22float2(hp[2]), f3 = __half22float2(hp[3]);
        a0 = w0 * f0.x; a1 = w0 * f0.y; a2 = w0 * f1.x; a3 = w0 * f1.y;
        a4 = w0 * f2.x; a5 = w0 * f2.y; a6 = w0 * f3.x; a7 = w0 * f3.y;
    }
#define ACC8(R, V)                                                          \
    {                                                                       \
        const __half2* hp = (const __half2*)&(V);                           \
        float2 f0 = __half22float2(hp[0]), f1 = __half22float2(hp[1]);      \
        float2 f2 = __half22float2(hp[2]), f3 = __half22float2(hp[3]);      \
        a0 = fmaf((R).w, f0.x, a0); a1 = fmaf((R).w, f0.y, a1);             \
        a2 = fmaf((R).w, f1.x, a2); a3 = fmaf((R).w, f1.y, a3);             \
        a4 = fmaf((R).w, f2.x, a4); a5 = fmaf((R).w, f2.y, a5);             \
        a6 = fmaf((R).w, f3.x, a6); a7 = fmaf((R).w, f3.y, a7);             \
    }
    int e = beg;
    int e4 = beg + ((end - beg) & ~3);
    for (; e < e4; e += 4) {
        ERec r0 = er[e], r1 = er[e + 1], r2 = er[e + 2], r3 = er[e + 3];
        float4 v0 = x[r0.c * 8 + li];
        float4 v1 = x[r1.c * 8 + li];
        float4 v2 = x[r2.c * 8 + li];
        float4 v3 = x[r3.c * 8 + li];
        ACC8(r0, v0); ACC8(r1, v1); ACC8(r2, v2); ACC8(r3, v3);
    }
    for (; e < end; ++e) {
        ERec r = er[e];
        float4 v = x[r.c * 8 + li];
        ACC8(r, v);
    }
#undef ACC8
    float4 ov;
    __half2* op = (__half2*)&ov;
    op[0] = __floats2half2_rn(a0, a1);
    op[1] = __floats2half2_rn(a2, a3);
    op[2] = __floats2half2_rn(a4, a5);
    op[3] = __floats2half2_rn(a6, a7);
    x_out[base] = ov;
    if (mode) {
        int hb = g * 16 + li * 2;
        float4 h0 = h4[hb], h1 = h4[hb + 1];
        h0.x = (h0.x + 0.95f * a0) * (1.0f / 16.0f);
        h0.y = (h0.y + 0.95f * a1) * (1.0f / 16.0f);
        h0.z = (h0.z + 0.95f * a2) * (1.0f / 16.0f);
        h0.w = (h0.w + 0.95f * a3) * (1.0f / 16.0f);
        h1.x = (h1.x + 0.95f * a4) * (1.0f / 16.0f);
        h1.y = (h1.y + 0.95f * a5) * (1.0f / 16.0f);
        h1.z = (h1.z + 0.95f * a6) * (1.0f / 16.0f);
        h1.w = (h1.w + 0.95f * a7) * (1.0f / 16.0f);
        if (mode == 2) {
            const float FC = 0.05f / 15.0f;  // analytic sum of all 16 feat terms
            float4 f0 = feat4[hb], f1 = feat4[hb + 1];
            h0.x = fmaf(FC, f0.x, h0.x); h0.y = fmaf(FC, f0.y, h0.y);
            h0.z = fmaf(FC, f0.z, h0.z); h0.w = fmaf(FC, f0.w, h0.w);
            h1.x = fmaf(FC, f1.x, h1.x); h1.y = fmaf(FC, f1.y, h1.y);
            h1.z = fmaf(FC, f1.z, h1.z); h1.w = fmaf(FC, f1.w, h1.w);
        }
        h4[hb] = h0; h4[hb + 1] = h1;
    }
}

// ---------- FC epilogue ----------
__global__ __launch_bounds__(256) void fc_kernel(const float* __restrict__ h,
                                                 const float* __restrict__ W,
                                                 const float* __restrict__ b,
                                                 float* __restrict__ out) {
    __shared__ float Ws[CC * 68];
    __shared__ float bs[CC];
    for (int j = threadIdx.x; j < CC * DD; j += 256) {
        int c = j >> 6, d = j & 63;
        Ws[c * 68 + d] = W[j];
    }
    if (threadIdx.x < CC) bs[threadIdx.x] = b[threadIdx.x];
    __syncthreads();
    int idx = blockIdx.x * 256 + threadIdx.x;
    if (idx >= NN * CC) return;
    int i = idx / CC, c = idx - i * CC;
    const float4* h4 = (const float4*)(h + (long)i * DD);
    const float* wr = Ws + c * 68;
    float acc = bs[c];
#pragma unroll
    for (int d2 = 0; d2 < 16; ++d2) {
        float4 a = h4[d2];
        acc = fmaf(a.x, wr[d2 * 4 + 0], acc);
        acc = fmaf(a.y, wr[d2 * 4 + 1], acc);
        acc = fmaf(a.z, wr[d2 * 4 + 2], acc);
        acc = fmaf(a.w, wr[d2 * 4 + 3], acc);
    }
    out[idx] = acc;
}

extern "C" void kernel_launch(void* const* d_in, const int* in_sizes, int n_in,
                              void* d_out, int out_size, void* d_ws, size_t ws_size,
                              hipStream_t stream) {
    const float* feat = (const float*)d_in[0];
    const float* W    = (const float*)d_in[1];
    const float* b    = (const float*)d_in[2];
    const int*   src  = (const int*)d_in[3];
    const int*   dst  = (const int*)d_in[4];
    float* out = (float*)d_out;

    char* p = (char*)d_ws;
    auto alloc = [&](size_t bytes) {
        char* r = p;
        p += (bytes + 255) & ~(size_t)255;
        return r;
    };
    int*      cnt     = (int*)alloc((size_t)NN * sizeof(int));
    int*      cursor  = (int*)alloc((size_t)NN * sizeof(int));
    float*    dinv    = (float*)alloc((size_t)NN * sizeof(float));
    int*      row_ptr = (int*)alloc((size_t)(NN + 1) * sizeof(int));
    int*      bsum    = (int*)alloc((size_t)SCAN_BLOCKS * sizeof(int));
    int*      boff    = (int*)alloc((size_t)SCAN_BLOCKS * sizeof(int));
    int*      perm    = (int*)alloc((size_t)EE * sizeof(int));
    int2*     er      = (int2*)alloc((size_t)EE * sizeof(int2));
    float4*   xh0     = (float4*)alloc((size_t)NN * 8 * sizeof(float4));
    float4*   xh1     = (float4*)alloc((size_t)NN * 8 * sizeof(float4));
    float*    h       = (float*)alloc((size_t)NN * DD * sizeof(float));

    hipMemsetAsync(cnt, 0, (size_t)NN * sizeof(int), stream);
    hipMemsetAsync(cursor, 0, (size_t)NN * sizeof(int), stream);
    hipMemsetAsync(h, 0, (size_t)NN * DD * sizeof(float), stream);

    deg_kernel<<<(EE + 255) / 256, 256, 0, stream>>>(dst, cnt);
    dinv_kernel<<<(NN + 255) / 256, 256, 0, stream>>>(cnt, dinv);
    scan1_kernel<<<SCAN_BLOCKS, 256, 0, stream>>>(cnt, row_ptr, bsum);
    scan2_kernel<<<1, 512, 0, stream>>>(bsum, boff);
    scan3_kernel<<<SCAN_BLOCKS, 256, 0, stream>>>(row_ptr, boff);
    perm_kernel<<<(EE + 255) / 256, 256, 0, stream>>>(dst, row_ptr, cursor, perm);
    build_kernel<<<(EE + 255) / 256, 256, 0, stream>>>(perm, src, dst, dinv, er);
    cvt_kernel<<<(NN * 32 + 255) / 256, 256, 0, stream>>>((const float2*)feat,
                                                          (__half2*)xh0);

    const float4* xs = xh0;
    float4* xd = xh1;
    for (int j = 0; j < KK; ++j) {
        int mode = (j >= 10) ? ((j == KK - 1) ? 2 : 1) : 0;
        // NN*8 = 800000 threads = 3125 blocks exactly
        spmm_step<<<3125, 256, 0, stream>>>(xs, xd, (float4*)h, (const float4*)feat,
                                            row_ptr, (const ERec*)er, dinv, mode);
        const float4* t = xd;
        xd = (xd == xh0) ? xh1 : xh0;
        xs = (float4*)t;
    }
    fc_kernel<<<(NN * CC + 255) / 256, 256, 0, stream>>>(h, W, b, out);
}